// Round 3
// baseline (358.521 us; speedup 1.0000x reference)
//
#include <hip/hip_runtime.h>

// StructuredLayer via chain-ordered dense micro-GEMMs, single-LDS-buffer version.
//
// Chain trick: 81*2225 == 1 (mod 4096); in chain order o(k)=2225k mod 4096 the
// 81-wide window of output o(k) starts exactly at column k. A 16-k tile is a
// dense 16x16x96 GEMM against x columns [16m, 16m+96) -> 3x mfma_f32_16x16x32_f16.
//
// LDS aliasing: waves process tiles m = 8*s + w (s = super-step, barrier each).
// After step s-1, x columns < 128s are dead; step-s results (chain k in
// [16m, 16m+16), m = 8s+w) are written at column pos = k - 128 < 128s, which is
// provably disjoint from every concurrent read (reads >= 128s). Step-0 results
// (k < 128) are held in registers and written post-loop at pos = k + 3968.
// Window wrap removed by duplicating x cols 0..95 at 4096..4191.
// Flush: out[t][o] = buf[(81*o - 128) & 4095] + bias[o], coalesced dwordx4.

typedef _Float16 h4 __attribute__((ext_vector_type(4)));
typedef _Float16 h8 __attribute__((ext_vector_type(8)));
typedef float f32x4 __attribute__((ext_vector_type(4)));

#define XS 4232   // row stride in halfs: 2116 dw == 4 (mod 32) -> rows spread banks

// ---------------- Pass 0: pack weights into w4[256][16][96] fp16 ----------------
// w4[m][n][kk] = Weff[o(16m+n)][(16m+kk)%4096] if kk in [n, n+81) else 0.
__global__ void __launch_bounds__(256) build_w4_kernel(
    const float* __restrict__ weight, const float* __restrict__ mask,
    const float* __restrict__ gauge, _Float16* __restrict__ w4) {
  int idx = blockIdx.x * 256 + threadIdx.x;   // grid covers 256*16*96 = 393216
  int kk = idx % 96;
  int n  = (idx / 96) & 15;
  int m  = idx / 1536;
  int k  = m * 16 + n;
  float v = 0.f;
  if (kk >= n && kk < n + 81) {
    int o   = (2225 * k) & 4095;
    int col = (m * 16 + kk) & 4095;
    size_t off = (size_t)o * 4096 + col;
    v = weight[off] * mask[off] * gauge[off];
  }
  w4[idx] = (_Float16)v;
}

// ---------------- Main kernel: 8 tokens/block, 8 waves, 32 super-steps ----------------
__global__ void __launch_bounds__(512, 4) spmm_mfma_kernel(
    const float* __restrict__ x, const _Float16* __restrict__ w4,
    const float* __restrict__ bias, float* __restrict__ out) {
  __shared__ __align__(16) _Float16 xl[8 * XS];   // 67,712 B -> 2 blocks/CU

  const int tid = threadIdx.x;
  const size_t t0 = (size_t)blockIdx.x * 8;

  // ---- stage x: 8 token rows f32 -> fp16 LDS, + duplicate cols 0..95 at 4096+
  const float4* xg = (const float4*)(x + t0 * 4096);
#pragma unroll
  for (int i = 0; i < 16; ++i) {
    int idx = i * 512 + tid;
    int row = idx >> 10, c4 = idx & 1023;
    float4 v = xg[idx];
    h4 hv = {(_Float16)v.x, (_Float16)v.y, (_Float16)v.z, (_Float16)v.w};
    *(h4*)&xl[row * XS + c4 * 4] = hv;
    if (c4 < 24) *(h4*)&xl[row * XS + 4096 + c4 * 4] = hv;
  }

  const int w = tid >> 6, lane = tid & 63;
  const int l15 = lane & 15, g = lane >> 4;     // k-group 0..3
  const int tA = l15 & 7;                       // token row (rows 8..15 duplicate)
  const _Float16* xrow = xl + tA * XS;
  // B fragment global address (halfs): (16m + l15)*96 + 8g (+32 per k-step)
  const _Float16* bbase = w4 + (size_t)l15 * 96 + 8 * g;

  // ---- B prefetch, depth 2: tiles m = 8s + w
  const _Float16* bp0 = bbase + (size_t)w * 1536;          // s=0
  const _Float16* bp1 = bbase + (size_t)(8 + w) * 1536;    // s=1
  h8 b00 = *(const h8*)(bp0), b01 = *(const h8*)(bp0 + 32), b02 = *(const h8*)(bp0 + 64);
  h8 b10 = *(const h8*)(bp1), b11 = *(const h8*)(bp1 + 32), b12 = *(const h8*)(bp1 + 64);

  float h0, h1, h2, h3;                          // step-0 results held (k < 128)

#pragma unroll 2
  for (int s = 0; s < 32; ++s) {
    const int m = 8 * s + w;
    const int K16 = m << 4;
    __syncthreads();                             // step s-1 reads done before our writes
    h8 a0 = *(const h8*)(xrow + K16 + 8 * g);
    h8 a1 = *(const h8*)(xrow + K16 + 32 + 8 * g);
    h8 a2 = *(const h8*)(xrow + K16 + 64 + 8 * g);
    // prefetch B for step s+2 (wraps harmlessly to valid tiles at the end)
    const _Float16* np = bbase + (size_t)(((m + 16) & 255)) * 1536;
    h8 nb0 = *(const h8*)(np), nb1 = *(const h8*)(np + 32), nb2 = *(const h8*)(np + 64);

    f32x4 acc = {0.f, 0.f, 0.f, 0.f};
    acc = __builtin_amdgcn_mfma_f32_16x16x32_f16(a0, b00, acc, 0, 0, 0);
    acc = __builtin_amdgcn_mfma_f32_16x16x32_f16(a1, b01, acc, 0, 0, 0);
    acc = __builtin_amdgcn_mfma_f32_16x16x32_f16(a2, b02, acc, 0, 0, 0);

    // C layout: col = lane&15 (= n), row = 4*(lane>>4)+r (= token; rows 8..15 dup)
    if (s == 0) {
      h0 = acc[0]; h1 = acc[1]; h2 = acc[2]; h3 = acc[3];
    } else if (lane < 32) {
      _Float16* op = xl + K16 + l15 - 128 + (g * 4) * XS;
#pragma unroll
      for (int r = 0; r < 4; ++r) op[r * XS] = (_Float16)acc[r];
    }
    b00 = b10; b01 = b11; b02 = b12;
    b10 = nb0; b11 = nb1; b12 = nb2;
  }

  __syncthreads();
  if (lane < 32) {                               // flush held step-0 results
    _Float16* op = xl + 16 * w + l15 + 3968 + (g * 4) * XS;
    op[0 * XS] = (_Float16)h0; op[1 * XS] = (_Float16)h1;
    op[2 * XS] = (_Float16)h2; op[3 * XS] = (_Float16)h3;
  }
  __syncthreads();

  // ---- flush: un-permute pos = (81*o - 128) & 4095, add bias, dwordx4 stores
  float* og = out + t0 * 4096;
#pragma unroll
  for (int it = 0; it < 16; ++it) {
    int e = (it * 512 + tid) * 4;
    int tt = e >> 12, o = e & 4095;
    const _Float16* row = xl + tt * XS;
    float4 bb = *(const float4*)(bias + o);
    float4 r;
    r.x = (float)row[(81 * o - 128) & 4095] + bb.x;
    r.y = (float)row[(81 * o - 47) & 4095] + bb.y;    // 81*(o+1)-128
    r.z = (float)row[(81 * o + 34) & 4095] + bb.z;    // 81*(o+2)-128
    r.w = (float)row[(81 * o + 115) & 4095] + bb.w;   // 81*(o+3)-128
    *(float4*)(og + e) = r;
  }
}

extern "C" void kernel_launch(void* const* d_in, const int* in_sizes, int n_in,
                              void* d_out, int out_size, void* d_ws, size_t ws_size,
                              hipStream_t stream) {
  const float* x      = (const float*)d_in[0];
  const float* weight = (const float*)d_in[1];
  const float* bias   = (const float*)d_in[2];
  const float* mask   = (const float*)d_in[3];
  const float* gauge  = (const float*)d_in[4];
  float* out = (float*)d_out;
  _Float16* w4 = (_Float16*)d_ws;   // 256*16*96*2 = 786,432 B of workspace

  build_w4_kernel<<<1536, 256, 0, stream>>>(weight, mask, gauge, w4);
  spmm_mfma_kernel<<<1024, 512, 0, stream>>>(x, w4, bias, out);
}

// Round 4
// 352.693 us; speedup vs baseline: 1.0165x; 1.0165x over previous
//
#include <hip/hip_runtime.h>

// StructuredLayer via chain-ordered dense micro-GEMMs.
// Chain trick: 81*2225 == 1 (mod 4096); in chain order o(k)=2225k mod 4096 the
// 81-wide window of output o(k) starts exactly at column k. A 16-k tile is a
// dense 16x16x96 GEMM vs x columns [16m,16m+96) -> 3x mfma_f32_16x16x32_f16.
//
// Round-4 changes vs round 3:
//  * x stage loads + out flush stores are NON-TEMPORAL (nt) so the 268 MB of
//    stream traffic stops evicting the 786 KB w4 array from per-XCD L2.
//  * B prefetch deepened to 4 super-steps (statically-indexed 4-way unroll).
// Structure (passed r3): 8 tokens/block, 8 waves, single aliased LDS buffer
// (results overwrite dead x columns), flush un-permutes k = (81*o-128)&4095.

typedef _Float16 h4 __attribute__((ext_vector_type(4)));
typedef _Float16 h8 __attribute__((ext_vector_type(8)));
typedef float f32x4 __attribute__((ext_vector_type(4)));

#define XS 4232   // LDS row stride in halfs: 2116 dw == 4 (mod 32)

// ---------------- Pass 0: pack weights into w4[256][16][96] fp16 ----------------
__global__ void __launch_bounds__(256) build_w4_kernel(
    const float* __restrict__ weight, const float* __restrict__ mask,
    const float* __restrict__ gauge, _Float16* __restrict__ w4) {
  int idx = blockIdx.x * 256 + threadIdx.x;   // grid covers 256*16*96 = 393216
  int kk = idx % 96;
  int n  = (idx / 96) & 15;
  int m  = idx / 1536;
  int k  = m * 16 + n;
  float v = 0.f;
  if (kk >= n && kk < n + 81) {
    int o   = (2225 * k) & 4095;
    int col = (m * 16 + kk) & 4095;
    size_t off = (size_t)o * 4096 + col;
    v = weight[off] * mask[off] * gauge[off];
  }
  w4[idx] = (_Float16)v;
}

// ---------------- Main kernel: 8 tokens/block, 8 waves, 32 super-steps ----------------
__global__ void __launch_bounds__(512, 4) spmm_mfma_kernel(
    const float* __restrict__ x, const _Float16* __restrict__ w4,
    const float* __restrict__ bias, float* __restrict__ out) {
  __shared__ __align__(16) _Float16 xl[8 * XS];   // 67,712 B -> 2 blocks/CU

  const int tid = threadIdx.x;
  const size_t t0 = (size_t)blockIdx.x * 8;

  // ---- stage x (nt loads): 8 rows f32 -> fp16 LDS, duplicate cols 0..95 at 4096+
  const f32x4* xg = (const f32x4*)(x + t0 * 4096);
#pragma unroll
  for (int i = 0; i < 16; ++i) {
    int idx = i * 512 + tid;
    int row = idx >> 10, c4 = idx & 1023;
    f32x4 v = __builtin_nontemporal_load(xg + idx);
    h4 hv = {(_Float16)v.x, (_Float16)v.y, (_Float16)v.z, (_Float16)v.w};
    *(h4*)&xl[row * XS + c4 * 4] = hv;
    if (c4 < 24) *(h4*)&xl[row * XS + 4096 + c4 * 4] = hv;
  }

  const int w = tid >> 6, lane = tid & 63;
  const int l15 = lane & 15, g = lane >> 4;     // k-group 0..3
  const int tA = l15 & 7;                       // token row (rows 8..15 duplicate)
  const _Float16* xrow = xl + tA * XS;
  // B fragment global address (halfs): (16m + l15)*96 + 8g (+32 per k-step)
  const _Float16* bbase = w4 + (size_t)l15 * 96 + 8 * g;

  // ---- B prefetch, depth 4: tiles m = 8s + w
  h8 bq0[3], bq1[3], bq2[3], bq3[3];
#pragma unroll
  for (int c = 0; c < 3; ++c) {
    bq0[c] = *(const h8*)(bbase + (size_t)(0  + w) * 1536 + 32 * c);
    bq1[c] = *(const h8*)(bbase + (size_t)(8  + w) * 1536 + 32 * c);
    bq2[c] = *(const h8*)(bbase + (size_t)(16 + w) * 1536 + 32 * c);
    bq3[c] = *(const h8*)(bbase + (size_t)(24 + w) * 1536 + 32 * c);
  }

  float h0, h1, h2, h3;                          // step-0 results held (k < 128)

#define STEP(J, B)                                                          \
  {                                                                         \
    const int s = su * 4 + J;                                               \
    const int m = 8 * s + w;                                                \
    const int K16 = m << 4;                                                 \
    __syncthreads(); /* step s-1 reads done before our writes */            \
    h8 a0 = *(const h8*)(xrow + K16 + 8 * g);                               \
    h8 a1 = *(const h8*)(xrow + K16 + 32 + 8 * g);                          \
    h8 a2 = *(const h8*)(xrow + K16 + 64 + 8 * g);                          \
    const _Float16* np = bbase + (size_t)((m + 32) & 255) * 1536;           \
    h8 n0 = *(const h8*)(np);                                               \
    h8 n1 = *(const h8*)(np + 32);                                          \
    h8 n2 = *(const h8*)(np + 64);                                          \
    f32x4 acc = {0.f, 0.f, 0.f, 0.f};                                       \
    acc = __builtin_amdgcn_mfma_f32_16x16x32_f16(a0, B[0], acc, 0, 0, 0);   \
    acc = __builtin_amdgcn_mfma_f32_16x16x32_f16(a1, B[1], acc, 0, 0, 0);   \
    acc = __builtin_amdgcn_mfma_f32_16x16x32_f16(a2, B[2], acc, 0, 0, 0);   \
    B[0] = n0; B[1] = n1; B[2] = n2;                                        \
    if (s == 0) {                                                           \
      h0 = acc[0]; h1 = acc[1]; h2 = acc[2]; h3 = acc[3];                   \
    } else if (lane < 32) {                                                 \
      /* C: col = lane&15 (= n), row = 4*(lane>>4)+r (= token, 8..15 dup) */\
      _Float16* op = xl + K16 + l15 - 128 + (g * 4) * XS;                   \
      op[0 * XS] = (_Float16)acc[0];                                        \
      op[1 * XS] = (_Float16)acc[1];                                        \
      op[2 * XS] = (_Float16)acc[2];                                        \
      op[3 * XS] = (_Float16)acc[3];                                        \
    }                                                                       \
  }

#pragma unroll 1
  for (int su = 0; su < 8; ++su) {
    STEP(0, bq0)
    STEP(1, bq1)
    STEP(2, bq2)
    STEP(3, bq3)
  }
#undef STEP

  __syncthreads();
  if (lane < 32) {                               // flush held step-0 results
    _Float16* op = xl + 16 * w + l15 + 3968 + (g * 4) * XS;
    op[0 * XS] = (_Float16)h0; op[1 * XS] = (_Float16)h1;
    op[2 * XS] = (_Float16)h2; op[3 * XS] = (_Float16)h3;
  }
  __syncthreads();

  // ---- flush: un-permute pos = (81*o - 128) & 4095, add bias, nt dwordx4 stores
  float* og = out + t0 * 4096;
#pragma unroll
  for (int it = 0; it < 16; ++it) {
    int e = (it * 512 + tid) * 4;
    int tt = e >> 12, o = e & 4095;
    const _Float16* row = xl + tt * XS;
    float4 bb = *(const float4*)(bias + o);
    f32x4 r;
    r.x = (float)row[(81 * o - 128) & 4095] + bb.x;
    r.y = (float)row[(81 * o - 47) & 4095] + bb.y;    // 81*(o+1)-128
    r.z = (float)row[(81 * o + 34) & 4095] + bb.z;    // 81*(o+2)-128
    r.w = (float)row[(81 * o + 115) & 4095] + bb.w;   // 81*(o+3)-128
    __builtin_nontemporal_store(r, (f32x4*)(og + e));
  }
}

extern "C" void kernel_launch(void* const* d_in, const int* in_sizes, int n_in,
                              void* d_out, int out_size, void* d_ws, size_t ws_size,
                              hipStream_t stream) {
  const float* x      = (const float*)d_in[0];
  const float* weight = (const float*)d_in[1];
  const float* bias   = (const float*)d_in[2];
  const float* mask   = (const float*)d_in[3];
  const float* gauge  = (const float*)d_in[4];
  float* out = (float*)d_out;
  _Float16* w4 = (_Float16*)d_ws;   // 256*16*96*2 = 786,432 B of workspace

  build_w4_kernel<<<1536, 256, 0, stream>>>(weight, mask, gauge, w4);
  spmm_mfma_kernel<<<1024, 512, 0, stream>>>(x, w4, bias, out);
}